// Round 5
// baseline (2745.304 us; speedup 1.0000x reference)
//
#include <hip/hip_runtime.h>
#include <hip/hip_bf16.h>

#define NI 784
#define NH 1024
#define NO 10
#define BATCH 512
#define TSTEPS 100

#define BM 128
#define BN 256
#define BK 16
#define LDA 132   // As row stride in floats (132*4B: +16B pad -> staging writes 2-way max)
#define LDB 260   // Bs row stride in floats

typedef __attribute__((ext_vector_type(4))) float floatx4;

__global__ __launch_bounds__(256) void init_ws_kernel(float* __restrict__ p, int n) {
  int i = blockIdx.x * 256 + threadIdx.x;
  if (i < n) p[i] = 0.0f;
}

// C[M,1024] = X[M,784] @ W1[1024,784]^T + b1, fp32.
// 128x256 tile, BK=16 (784=49*16). 256 threads, 16x8 micro-tile each.
// All LDS fragment reads are lane-consecutive 16B chunks (m134 baseline, no
// 4-way conflicts). K-accumulation strictly sequential fmaf -> bit-identical
// to round-3/4 (absmax 0.0 preserved).
__global__ __launch_bounds__(256, 2) void sgemm1_kernel(
    const float* __restrict__ X,
    const float* __restrict__ W1,
    const float* __restrict__ b1,
    float* __restrict__ C)
{
  __shared__ __align__(16) float As[BK * LDA];
  __shared__ __align__(16) float Bs[BK * LDB];

  const int tid = threadIdx.x;
  const int tx = tid & 31;            // n-direction, 0..31 (lane-consecutive)
  const int ty = tid >> 5;            // m-direction, 0..7
  const int n0 = blockIdx.x * BN;     // 4 n-blocks
  const int m0 = blockIdx.y * BM;

  const int srow  = tid >> 2;         // 0..63 staging row
  const int skcol = (tid & 3) * 4;    // 0,4,8,12 staging k-offset

  float acc[16][8];
#pragma unroll
  for (int i = 0; i < 16; ++i)
#pragma unroll
    for (int j = 0; j < 8; ++j) acc[i][j] = 0.0f;

  const float* Xs  = X  + (size_t)m0 * NI + skcol;
  const float* W1s = W1 + (size_t)n0 * NI + skcol;

  // prefetch tile 0
  floatx4 xa0 = *(const floatx4*)&Xs [(size_t)(srow)      * NI];
  floatx4 xa1 = *(const floatx4*)&Xs [(size_t)(64 + srow) * NI];
  floatx4 wq0 = *(const floatx4*)&W1s[(size_t)(srow)       * NI];
  floatx4 wq1 = *(const floatx4*)&W1s[(size_t)(64 + srow)  * NI];
  floatx4 wq2 = *(const floatx4*)&W1s[(size_t)(128 + srow) * NI];
  floatx4 wq3 = *(const floatx4*)&W1s[(size_t)(192 + srow) * NI];

  for (int kt = 0; kt < NI / BK; ++kt) {
    __syncthreads();                  // previous tile fully consumed
#pragma unroll
    for (int e = 0; e < 4; ++e) {
      As[(skcol + e) * LDA + srow]       = xa0[e];
      As[(skcol + e) * LDA + 64 + srow]  = xa1[e];
      Bs[(skcol + e) * LDB + srow]       = wq0[e];
      Bs[(skcol + e) * LDB + 64 + srow]  = wq1[e];
      Bs[(skcol + e) * LDB + 128 + srow] = wq2[e];
      Bs[(skcol + e) * LDB + 192 + srow] = wq3[e];
    }
    __syncthreads();

    if (kt + 1 < NI / BK) {           // prefetch next tile; overlaps compute
      const int k0 = (kt + 1) * BK;
      xa0 = *(const floatx4*)&Xs [(size_t)(srow)      * NI + k0];
      xa1 = *(const floatx4*)&Xs [(size_t)(64 + srow) * NI + k0];
      wq0 = *(const floatx4*)&W1s[(size_t)(srow)       * NI + k0];
      wq1 = *(const floatx4*)&W1s[(size_t)(64 + srow)  * NI + k0];
      wq2 = *(const floatx4*)&W1s[(size_t)(128 + srow) * NI + k0];
      wq3 = *(const floatx4*)&W1s[(size_t)(192 + srow) * NI + k0];
    }

#pragma unroll
    for (int k = 0; k < BK; ++k) {
      floatx4 av[4], bv[2];
#pragma unroll
      for (int h = 0; h < 4; ++h)
        av[h] = *(const floatx4*)&As[k * LDA + 32 * h + ty * 4];  // 2 uniq/wave: broadcast
#pragma unroll
      for (int g = 0; g < 2; ++g)
        bv[g] = *(const floatx4*)&Bs[k * LDB + 128 * g + tx * 4]; // stride-1 b128
#pragma unroll
      for (int h = 0; h < 4; ++h)
#pragma unroll
        for (int i = 0; i < 4; ++i)
#pragma unroll
          for (int g = 0; g < 2; ++g)
#pragma unroll
            for (int j = 0; j < 4; ++j)
              acc[h * 4 + i][g * 4 + j] =
                  fmaf(av[h][i], bv[g][j], acc[h * 4 + i][g * 4 + j]);
    }
  }

#pragma unroll
  for (int h = 0; h < 4; ++h)
#pragma unroll
    for (int i = 0; i < 4; ++i) {
      const int m = m0 + 32 * h + ty * 4 + i;
#pragma unroll
      for (int g = 0; g < 2; ++g) {
        const int n = n0 + 128 * g + tx * 4;
        floatx4 v;
#pragma unroll
        for (int j = 0; j < 4; ++j) v[j] = acc[h * 4 + i][g * 4 + j] + b1[n + j];
        *(floatx4*)&C[(size_t)m * NH + n] = v;   // 32 lanes x 16B consecutive
      }
    }
}

// One block per batch row; mem1 (4 f32/thread) and mem2 (tid<10) in registers;
// W2 columns in registers; c(t+1) software-prefetched.
__global__ __launch_bounds__(256) void recur_kernel(
    const float* __restrict__ cur1,      // [tc*512, 1024] fp32
    const float* __restrict__ W2,        // [10,1024]
    const float* __restrict__ b2,        // [10]
    float* __restrict__ mem1s,           // [512,1024]
    float* __restrict__ mem2s,           // [512,10]
    float* __restrict__ out,             // [100*512*10 spk | 512*10 mem2]
    long long out_size, int t0, int tc, int last)
{
  const int b    = blockIdx.x;
  const int tid  = threadIdx.x;
  const int lane = tid & 63;
  const int wave = tid >> 6;

  __shared__ float red[4][NO];

  float w[4][NO];
#pragma unroll
  for (int j = 0; j < 4; ++j)
#pragma unroll
    for (int o = 0; o < NO; ++o)
      w[j][o] = W2[o * NH + tid * 4 + j];

  floatx4 m1 = *(const floatx4*)&mem1s[(size_t)b * NH + tid * 4];
  float m2 = 0.0f, bb = 0.0f;
  if (tid < NO) {
    m2 = mem2s[b * NO + tid];
    bb = b2[tid];
  }

  const floatx4* c4 = (const floatx4*)cur1;
  floatx4 c = c4[((size_t)0 * BATCH + b) * (NH / 4) + tid];

  for (int t = 0; t < tc; ++t) {
    floatx4 cn = {0.f, 0.f, 0.f, 0.f};
    if (t + 1 < tc) cn = c4[((size_t)(t + 1) * BATCH + b) * (NH / 4) + tid];

    float a[NO];
#pragma unroll
    for (int o = 0; o < NO; ++o) a[o] = 0.0f;

#pragma unroll
    for (int j = 0; j < 4; ++j) {
      float mj = m1[j];
      float reset = (mj > 1.0f) ? 1.0f : 0.0f;   // reset from PREVIOUS mem1
      mj = 0.9f * mj + c[j] - reset;
      m1[j] = mj;
      float s = (mj > 1.0f) ? 1.0f : 0.0f;       // spike from NEW mem1
#pragma unroll
      for (int o = 0; o < NO; ++o) a[o] = fmaf(s, w[j][o], a[o]);
    }

#pragma unroll
    for (int m = 1; m <= 32; m <<= 1)
#pragma unroll
      for (int o = 0; o < NO; ++o) a[o] += __shfl_xor(a[o], m, 64);

    if (lane == 0) {
#pragma unroll
      for (int o = 0; o < NO; ++o) red[wave][o] = a[o];
    }
    __syncthreads();

    if (tid < NO) {
      float cur2 = red[0][tid] + red[1][tid] + red[2][tid] + red[3][tid] + bb;
      float reset2 = (m2 > 1.0f) ? 1.0f : 0.0f;
      m2 = 0.9f * m2 + cur2 - reset2;
      float spk2 = (m2 > 1.0f) ? 1.0f : 0.0f;
      long long idx = ((long long)(t0 + t) * BATCH + b) * NO + tid;
      if (idx < out_size) out[idx] = spk2;
    }
    __syncthreads();
    c = cn;
  }

  *(floatx4*)&mem1s[(size_t)b * NH + tid * 4] = m1;
  if (tid < NO) {
    mem2s[b * NO + tid] = m2;
    if (last) {
      long long idx = (long long)TSTEPS * BATCH * NO + b * NO + tid;
      if (idx < out_size) out[idx] = m2;
    }
  }
}

// Proven round-3 fallback (only if workspace is too small for the GEMM path).
__global__ __launch_bounds__(256) void fused_fp32_kernel(
    const float* __restrict__ x,
    const float* __restrict__ W1,
    const float* __restrict__ b1,
    const float* __restrict__ W2,
    const float* __restrict__ b2,
    float* __restrict__ out, long long out_size)
{
  const int b    = blockIdx.x;
  const int tid  = threadIdx.x;
  const int lane = tid & 63;
  const int wave = tid >> 6;

  __shared__ __align__(16) float xs[NI + 4];
  __shared__ float red[4][NO];

  float w[4][NO];
#pragma unroll
  for (int j = 0; j < 4; ++j)
#pragma unroll
    for (int o = 0; o < NO; ++o)
      w[j][o] = W2[o * NH + tid * 4 + j];

  float bias1[4];
#pragma unroll
  for (int j = 0; j < 4; ++j) bias1[j] = b1[tid * 4 + j];

  float m1[4] = {0.f, 0.f, 0.f, 0.f};
  float m2 = 0.0f, bb = 0.0f;
  if (tid < NO) bb = b2[tid];

  for (int t = 0; t < TSTEPS; ++t) {
    if (tid < 196)
      *(floatx4*)&xs[tid * 4] = *(const floatx4*)&x[((size_t)t * BATCH + b) * NI + tid * 4];
    __syncthreads();

    float a[NO];
#pragma unroll
    for (int o = 0; o < NO; ++o) a[o] = 0.0f;

#pragma unroll
    for (int j = 0; j < 4; ++j) {
      const float* wr = W1 + (size_t)(tid * 4 + j) * NI;
      float dot = 0.0f;
      for (int cch = 0; cch < 196; ++cch) {
        floatx4 wv = *(const floatx4*)&wr[cch * 4];
        floatx4 xv = *(const floatx4*)&xs[cch * 4];
#pragma unroll
        for (int e = 0; e < 4; ++e) dot = fmaf(wv[e], xv[e], dot);
      }
      float cur = dot + bias1[j];
      float mj = m1[j];
      float reset = (mj > 1.0f) ? 1.0f : 0.0f;
      mj = 0.9f * mj + cur - reset;
      m1[j] = mj;
      float s = (mj > 1.0f) ? 1.0f : 0.0f;
#pragma unroll
      for (int o = 0; o < NO; ++o) a[o] = fmaf(s, w[j][o], a[o]);
    }

#pragma unroll
    for (int m = 1; m <= 32; m <<= 1)
#pragma unroll
      for (int o = 0; o < NO; ++o) a[o] += __shfl_xor(a[o], m, 64);

    if (lane == 0) {
#pragma unroll
      for (int o = 0; o < NO; ++o) red[wave][o] = a[o];
    }
    __syncthreads();

    if (tid < NO) {
      float cur2 = red[0][tid] + red[1][tid] + red[2][tid] + red[3][tid] + bb;
      float reset2 = (m2 > 1.0f) ? 1.0f : 0.0f;
      m2 = 0.9f * m2 + cur2 - reset2;
      float spk2 = (m2 > 1.0f) ? 1.0f : 0.0f;
      long long idx = ((long long)t * BATCH + b) * NO + tid;
      if (idx < out_size) out[idx] = spk2;
    }
    __syncthreads();
  }

  if (tid < NO) {
    long long idx = (long long)TSTEPS * BATCH * NO + b * NO + tid;
    if (idx < out_size) out[idx] = m2;
  }
}

extern "C" void kernel_launch(void* const* d_in, const int* in_sizes, int n_in,
                              void* d_out, int out_size, void* d_ws, size_t ws_size,
                              hipStream_t stream) {
  const float* x  = (const float*)d_in[0];
  const float* W1 = (const float*)d_in[1];
  const float* b1 = (const float*)d_in[2];
  const float* W2 = (const float*)d_in[3];
  const float* b2 = (const float*)d_in[4];
  float* out = (float*)d_out;

  const size_t mem1_bytes = (size_t)BATCH * NH * 4;
  const size_t mem2_bytes = (size_t)BATCH * NO * 4;
  size_t fixed = (mem1_bytes + mem2_bytes + 255) & ~(size_t)255;
  const size_t per_step = (size_t)BATCH * NH * 4;   // 2 MB fp32 per timestep

  if (d_ws == nullptr || ws_size < fixed + per_step) {
    fused_fp32_kernel<<<BATCH, 256, 0, stream>>>(x, W1, b1, W2, b2, out,
                                                 (long long)out_size);
    return;
  }

  char* ws = (char*)d_ws;
  float* mem1s = (float*)ws;
  float* mem2s = (float*)(ws + mem1_bytes);
  float* cur1  = (float*)(ws + fixed);

  int Tc = (int)((ws_size - fixed) / per_step);
  if (Tc > TSTEPS) Tc = TSTEPS;

  const int nInit = BATCH * NH + BATCH * NO;
  init_ws_kernel<<<(nInit + 255) / 256, 256, 0, stream>>>((float*)ws, nInit);

  for (int t0 = 0; t0 < TSTEPS; t0 += Tc) {
    const int tc = (TSTEPS - t0 < Tc) ? (TSTEPS - t0) : Tc;
    const int M = tc * BATCH;                    // multiple of 128
    dim3 g(NH / BN, M / BM);
    sgemm1_kernel<<<g, 256, 0, stream>>>(x + (size_t)t0 * BATCH * NI, W1, b1, cur1);
    recur_kernel<<<BATCH, 256, 0, stream>>>(cur1, W2, b2, mem1s, mem2s, out,
                                            (long long)out_size, t0, tc,
                                            (t0 + tc >= TSTEPS) ? 1 : 0);
  }
}

// Round 6
// 1282.737 us; speedup vs baseline: 2.1402x; 2.1402x over previous
//
#include <hip/hip_runtime.h>
#include <hip/hip_bf16.h>

#define NI 784
#define NH 1024
#define NO 10
#define BATCH 512
#define TSTEPS 100

#define BM 128
#define BN 128
#define BK 16
#define LDT 132   // LDS row stride in floats; (skcol)*132+srow -> 2-way writes (free)

typedef __attribute__((ext_vector_type(4))) float floatx4;

__global__ __launch_bounds__(256) void init_ws_kernel(float* __restrict__ p, int n) {
  int i = blockIdx.x * 256 + threadIdx.x;
  if (i < n) p[i] = 0.0f;
}

// C[M,1024] = X[M,784] @ W1[1024,784]^T + b1, fp32.
// 128x128 tile, BK=16 (784=49*16). 256 threads, 8x8 micro-tile each.
// B-fragment cols per thread: {tx*4..+3} u {64+tx*4..+3} -> both LDS reads are
// 16 consecutive 16B chunks over banks 0..31 (2-way aliasing = free, m136).
// A-fragment: 4 unique broadcast addrs/wave, banks {0,8,16,24} = 1 phase.
// K-accumulation strictly sequential fmaf -> bit-identical to rounds 3/4.
__global__ __launch_bounds__(256) void sgemm1_kernel(
    const float* __restrict__ X,
    const float* __restrict__ W1,
    const float* __restrict__ b1,
    float* __restrict__ C)
{
  __shared__ __align__(16) float As[BK * LDT];
  __shared__ __align__(16) float Bs[BK * LDT];

  const int tid = threadIdx.x;
  const int tx = tid & 15;            // n-direction group (0..15)
  const int ty = tid >> 4;            // m-direction group (0..15)
  const int n0 = blockIdx.x * BN;
  const int m0 = blockIdx.y * BM;

  const int srow  = tid >> 2;         // 0..63 staging row
  const int skcol = (tid & 3) * 4;    // 0,4,8,12 staging k-offset

  float acc[8][8];
#pragma unroll
  for (int i = 0; i < 8; ++i)
#pragma unroll
    for (int j = 0; j < 8; ++j) acc[i][j] = 0.0f;

  const float* Xs  = X  + (size_t)m0 * NI + skcol;
  const float* W1s = W1 + (size_t)n0 * NI + skcol;

  // prefetch tile 0 into registers
  floatx4 xa0 = *(const floatx4*)&Xs [(size_t)(srow)      * NI];
  floatx4 xa1 = *(const floatx4*)&Xs [(size_t)(64 + srow) * NI];
  floatx4 wq0 = *(const floatx4*)&W1s[(size_t)(srow)      * NI];
  floatx4 wq1 = *(const floatx4*)&W1s[(size_t)(64 + srow) * NI];

  for (int kt = 0; kt < NI / BK; ++kt) {
    __syncthreads();                  // previous tile fully consumed
#pragma unroll
    for (int e = 0; e < 4; ++e) {
      As[(skcol + e) * LDT + srow]      = xa0[e];
      As[(skcol + e) * LDT + 64 + srow] = xa1[e];
      Bs[(skcol + e) * LDT + srow]      = wq0[e];
      Bs[(skcol + e) * LDT + 64 + srow] = wq1[e];
    }
    __syncthreads();

    if (kt + 1 < NI / BK) {           // prefetch next tile; overlaps compute
      const int k0 = (kt + 1) * BK;
      xa0 = *(const floatx4*)&Xs [(size_t)(srow)      * NI + k0];
      xa1 = *(const floatx4*)&Xs [(size_t)(64 + srow) * NI + k0];
      wq0 = *(const floatx4*)&W1s[(size_t)(srow)      * NI + k0];
      wq1 = *(const floatx4*)&W1s[(size_t)(64 + srow) * NI + k0];
    }

#pragma unroll
    for (int k = 0; k < BK; ++k) {
      const floatx4 av0 = *(const floatx4*)&As[k * LDT + ty * 8];
      const floatx4 av1 = *(const floatx4*)&As[k * LDT + ty * 8 + 4];
      const floatx4 bv0 = *(const floatx4*)&Bs[k * LDT + tx * 4];        // 2-way, free
      const floatx4 bv1 = *(const floatx4*)&Bs[k * LDT + 64 + tx * 4];   // 2-way, free
      const float a[8] = {av0[0], av0[1], av0[2], av0[3],
                          av1[0], av1[1], av1[2], av1[3]};
#pragma unroll
      for (int i = 0; i < 8; ++i)
#pragma unroll
        for (int j = 0; j < 4; ++j) {
          acc[i][j]     = fmaf(a[i], bv0[j], acc[i][j]);
          acc[i][4 + j] = fmaf(a[i], bv1[j], acc[i][4 + j]);
        }
    }
  }

#pragma unroll
  for (int i = 0; i < 8; ++i) {
    const int m = m0 + ty * 8 + i;
    floatx4 v0, v1;
#pragma unroll
    for (int j = 0; j < 4; ++j) {
      v0[j] = acc[i][j]     + b1[n0 + tx * 4 + j];
      v1[j] = acc[i][4 + j] + b1[n0 + 64 + tx * 4 + j];
    }
    *(floatx4*)&C[(size_t)m * NH + n0 + tx * 4]      = v0;
    *(floatx4*)&C[(size_t)m * NH + n0 + 64 + tx * 4] = v1;
  }
}

// One block per batch row; mem1 (4 f32/thread) and mem2 (tid<10) in registers;
// W2 columns in registers; c(t+1) software-prefetched.
__global__ __launch_bounds__(256) void recur_kernel(
    const float* __restrict__ cur1,      // [tc*512, 1024] fp32
    const float* __restrict__ W2,        // [10,1024]
    const float* __restrict__ b2,        // [10]
    float* __restrict__ mem1s,           // [512,1024]
    float* __restrict__ mem2s,           // [512,10]
    float* __restrict__ out,             // [100*512*10 spk | 512*10 mem2]
    long long out_size, int t0, int tc, int last)
{
  const int b    = blockIdx.x;
  const int tid  = threadIdx.x;
  const int lane = tid & 63;
  const int wave = tid >> 6;

  __shared__ float red[4][NO];

  float w[4][NO];
#pragma unroll
  for (int j = 0; j < 4; ++j)
#pragma unroll
    for (int o = 0; o < NO; ++o)
      w[j][o] = W2[o * NH + tid * 4 + j];

  floatx4 m1 = *(const floatx4*)&mem1s[(size_t)b * NH + tid * 4];
  float m2 = 0.0f, bb = 0.0f;
  if (tid < NO) {
    m2 = mem2s[b * NO + tid];
    bb = b2[tid];
  }

  const floatx4* c4 = (const floatx4*)cur1;
  floatx4 c = c4[((size_t)0 * BATCH + b) * (NH / 4) + tid];

  for (int t = 0; t < tc; ++t) {
    floatx4 cn = {0.f, 0.f, 0.f, 0.f};
    if (t + 1 < tc) cn = c4[((size_t)(t + 1) * BATCH + b) * (NH / 4) + tid];

    float a[NO];
#pragma unroll
    for (int o = 0; o < NO; ++o) a[o] = 0.0f;

#pragma unroll
    for (int j = 0; j < 4; ++j) {
      float mj = m1[j];
      float reset = (mj > 1.0f) ? 1.0f : 0.0f;   // reset from PREVIOUS mem1
      mj = 0.9f * mj + c[j] - reset;
      m1[j] = mj;
      float s = (mj > 1.0f) ? 1.0f : 0.0f;       // spike from NEW mem1
#pragma unroll
      for (int o = 0; o < NO; ++o) a[o] = fmaf(s, w[j][o], a[o]);
    }

#pragma unroll
    for (int m = 1; m <= 32; m <<= 1)
#pragma unroll
      for (int o = 0; o < NO; ++o) a[o] += __shfl_xor(a[o], m, 64);

    if (lane == 0) {
#pragma unroll
      for (int o = 0; o < NO; ++o) red[wave][o] = a[o];
    }
    __syncthreads();

    if (tid < NO) {
      float cur2 = red[0][tid] + red[1][tid] + red[2][tid] + red[3][tid] + bb;
      float reset2 = (m2 > 1.0f) ? 1.0f : 0.0f;
      m2 = 0.9f * m2 + cur2 - reset2;
      float spk2 = (m2 > 1.0f) ? 1.0f : 0.0f;
      long long idx = ((long long)(t0 + t) * BATCH + b) * NO + tid;
      if (idx < out_size) out[idx] = spk2;
    }
    __syncthreads();
    c = cn;
  }

  *(floatx4*)&mem1s[(size_t)b * NH + tid * 4] = m1;
  if (tid < NO) {
    mem2s[b * NO + tid] = m2;
    if (last) {
      long long idx = (long long)TSTEPS * BATCH * NO + b * NO + tid;
      if (idx < out_size) out[idx] = m2;
    }
  }
}

// Proven round-3 fallback (only if workspace is too small for the GEMM path).
__global__ __launch_bounds__(256) void fused_fp32_kernel(
    const float* __restrict__ x,
    const float* __restrict__ W1,
    const float* __restrict__ b1,
    const float* __restrict__ W2,
    const float* __restrict__ b2,
    float* __restrict__ out, long long out_size)
{
  const int b    = blockIdx.x;
  const int tid  = threadIdx.x;
  const int lane = tid & 63;
  const int wave = tid >> 6;

  __shared__ __align__(16) float xs[NI + 4];
  __shared__ float red[4][NO];

  float w[4][NO];
#pragma unroll
  for (int j = 0; j < 4; ++j)
#pragma unroll
    for (int o = 0; o < NO; ++o)
      w[j][o] = W2[o * NH + tid * 4 + j];

  float bias1[4];
#pragma unroll
  for (int j = 0; j < 4; ++j) bias1[j] = b1[tid * 4 + j];

  float m1[4] = {0.f, 0.f, 0.f, 0.f};
  float m2 = 0.0f, bb = 0.0f;
  if (tid < NO) bb = b2[tid];

  for (int t = 0; t < TSTEPS; ++t) {
    if (tid < 196)
      *(floatx4*)&xs[tid * 4] = *(const floatx4*)&x[((size_t)t * BATCH + b) * NI + tid * 4];
    __syncthreads();

    float a[NO];
#pragma unroll
    for (int o = 0; o < NO; ++o) a[o] = 0.0f;

#pragma unroll
    for (int j = 0; j < 4; ++j) {
      const float* wr = W1 + (size_t)(tid * 4 + j) * NI;
      float dot = 0.0f;
      for (int cch = 0; cch < 196; ++cch) {
        floatx4 wv = *(const floatx4*)&wr[cch * 4];
        floatx4 xv = *(const floatx4*)&xs[cch * 4];
#pragma unroll
        for (int e = 0; e < 4; ++e) dot = fmaf(wv[e], xv[e], dot);
      }
      float cur = dot + bias1[j];
      float mj = m1[j];
      float reset = (mj > 1.0f) ? 1.0f : 0.0f;
      mj = 0.9f * mj + cur - reset;
      m1[j] = mj;
      float s = (mj > 1.0f) ? 1.0f : 0.0f;
#pragma unroll
      for (int o = 0; o < NO; ++o) a[o] = fmaf(s, w[j][o], a[o]);
    }

#pragma unroll
    for (int m = 1; m <= 32; m <<= 1)
#pragma unroll
      for (int o = 0; o < NO; ++o) a[o] += __shfl_xor(a[o], m, 64);

    if (lane == 0) {
#pragma unroll
      for (int o = 0; o < NO; ++o) red[wave][o] = a[o];
    }
    __syncthreads();

    if (tid < NO) {
      float cur2 = red[0][tid] + red[1][tid] + red[2][tid] + red[3][tid] + bb;
      float reset2 = (m2 > 1.0f) ? 1.0f : 0.0f;
      m2 = 0.9f * m2 + cur2 - reset2;
      float spk2 = (m2 > 1.0f) ? 1.0f : 0.0f;
      long long idx = ((long long)t * BATCH + b) * NO + tid;
      if (idx < out_size) out[idx] = spk2;
    }
    __syncthreads();
  }

  if (tid < NO) {
    long long idx = (long long)TSTEPS * BATCH * NO + b * NO + tid;
    if (idx < out_size) out[idx] = m2;
  }
}

extern "C" void kernel_launch(void* const* d_in, const int* in_sizes, int n_in,
                              void* d_out, int out_size, void* d_ws, size_t ws_size,
                              hipStream_t stream) {
  const float* x  = (const float*)d_in[0];
  const float* W1 = (const float*)d_in[1];
  const float* b1 = (const float*)d_in[2];
  const float* W2 = (const float*)d_in[3];
  const float* b2 = (const float*)d_in[4];
  float* out = (float*)d_out;

  const size_t mem1_bytes = (size_t)BATCH * NH * 4;
  const size_t mem2_bytes = (size_t)BATCH * NO * 4;
  size_t fixed = (mem1_bytes + mem2_bytes + 255) & ~(size_t)255;
  const size_t per_step = (size_t)BATCH * NH * 4;   // 2 MB fp32 per timestep

  if (d_ws == nullptr || ws_size < fixed + per_step) {
    fused_fp32_kernel<<<BATCH, 256, 0, stream>>>(x, W1, b1, W2, b2, out,
                                                 (long long)out_size);
    return;
  }

  char* ws = (char*)d_ws;
  float* mem1s = (float*)ws;
  float* mem2s = (float*)(ws + mem1_bytes);
  float* cur1  = (float*)(ws + fixed);

  int Tc = (int)((ws_size - fixed) / per_step);
  if (Tc > TSTEPS) Tc = TSTEPS;

  const int nInit = BATCH * NH + BATCH * NO;
  init_ws_kernel<<<(nInit + 255) / 256, 256, 0, stream>>>((float*)ws, nInit);

  for (int t0 = 0; t0 < TSTEPS; t0 += Tc) {
    const int tc = (TSTEPS - t0 < Tc) ? (TSTEPS - t0) : Tc;
    const int M = tc * BATCH;                    // multiple of 128
    dim3 g(NH / BN, M / BM);
    sgemm1_kernel<<<g, 256, 0, stream>>>(x + (size_t)t0 * BATCH * NI, W1, b1, cur1);
    recur_kernel<<<BATCH, 256, 0, stream>>>(cur1, W2, b2, mem1s, mem2s, out,
                                            (long long)out_size, t0, tc,
                                            (t0 + tc >= TSTEPS) ? 1 : 0);
  }
}